// Round 14
// baseline (152.403 us; speedup 1.0000x reference)
//
#include <hip/hip_runtime.h>
#include <hip/hip_cooperative_groups.h>

namespace cg = cooperative_groups;

#define KK 4
#define TT 100000
#define NCLS 100
#define NN 4096
#define MARGIN_F 0.2f
#define EPS_F 1e-8f

#define NXCD 8
#define NCOPY 64
#define ACC_FLOATS (NCOPY * 16)
#define ACC_BYTES (ACC_FLOATS * 4)    // 4 KB
#define HB_BYTES (NN * KK * 128)      // fp8 batch, 2 MB (row = 128 B = 1 line)

// cooperative path geometry
#define CO_BLOCKS 512                 // 2 blocks/CU -> co-residency guaranteed
#define CO_WAVES_K 512                // (512/8)=64 blk/xcd * 2 xcd/k * 4 waves
#define CO_ITERS 13                   // ceil(6250 / 512)
#define BATCHES_K 6250                // 6250 * 16 = 100000 triplets per k

// fallback (R11) geometry
#define FB_BPK 782
#define FB_NBLOCKS (FB_BPK * NXCD)    // 6256

typedef float f32x4 __attribute__((ext_vector_type(4)));
typedef float f32x2 __attribute__((ext_vector_type(2)));

// ---------- shared device helpers ----------
__device__ __forceinline__ void fp8_pack_and_sq(
    const float4 v0, const float4 v1, unsigned& lo, unsigned& hi, float& sq)
{
    int l = 0, h = 0;
    l = __builtin_amdgcn_cvt_pk_fp8_f32(v0.x, v0.y, l, false);
    l = __builtin_amdgcn_cvt_pk_fp8_f32(v0.z, v0.w, l, true);
    h = __builtin_amdgcn_cvt_pk_fp8_f32(v1.x, v1.y, h, false);
    h = __builtin_amdgcn_cvt_pk_fp8_f32(v1.z, v1.w, h, true);
    lo = (unsigned)l; hi = (unsigned)h;
    const f32x2 d0 = __builtin_amdgcn_cvt_pk_f32_fp8(l, false);
    const f32x2 d1 = __builtin_amdgcn_cvt_pk_f32_fp8(l, true);
    const f32x2 d2 = __builtin_amdgcn_cvt_pk_f32_fp8(h, false);
    const f32x2 d3 = __builtin_amdgcn_cvt_pk_f32_fp8(h, true);
    sq += d0.x * d0.x + d0.y * d0.y + d1.x * d1.x + d1.y * d1.y
        + d2.x * d2.x + d2.y * d2.y + d3.x * d3.x + d3.y * d3.y;
}

// triplet body: returns {loss, count-flag} on the diagonal lane
__device__ __forceinline__ void tri_mfma(
    const unsigned char* __restrict__ hb, const float2* __restrict__ tbl_k,
    const int k, const int i0, const int i1, const int i2,
    const int c, const int h, const bool bvalid, float& lt, float& lc)
{
    const unsigned char* ra = hb + (((long long)(i0 << 2) + k) << 7);
    const unsigned char* rp = hb + (((long long)(i1 << 2) + k) << 7);
    const unsigned char* rn = hb + (((long long)(i2 << 2) + k) << 7);
    const int ho = h * 8;

    const long a0 = *(const long*)(ra + ho);
    const long a1 = *(const long*)(ra + 32 + ho);
    const long a2 = *(const long*)(ra + 64 + ho);
    const long a3 = *(const long*)(ra + 96 + ho);
    const long p0 = *(const long*)(rp + ho);
    const long p1 = *(const long*)(rp + 32 + ho);
    const long p2 = *(const long*)(rp + 64 + ho);
    const long p3 = *(const long*)(rp + 96 + ho);
    const long n0 = *(const long*)(rn + ho);
    const long n1 = *(const long*)(rn + 32 + ho);
    const long n2 = *(const long*)(rn + 64 + ho);
    const long n3 = *(const long*)(rn + 96 + ho);
    const float2 ta = tbl_k[i0];
    const float2 tq = tbl_k[i1];
    const float2 tn = tbl_k[i2];

    f32x4 acc_p = {0.f, 0.f, 0.f, 0.f};
    f32x4 acc_n = {0.f, 0.f, 0.f, 0.f};
    acc_p = __builtin_amdgcn_mfma_f32_16x16x32_fp8_fp8(a0, p0, acc_p, 0, 0, 0);
    acc_n = __builtin_amdgcn_mfma_f32_16x16x32_fp8_fp8(a0, n0, acc_n, 0, 0, 0);
    acc_p = __builtin_amdgcn_mfma_f32_16x16x32_fp8_fp8(a1, p1, acc_p, 0, 0, 0);
    acc_n = __builtin_amdgcn_mfma_f32_16x16x32_fp8_fp8(a1, n1, acc_n, 0, 0, 0);
    acc_p = __builtin_amdgcn_mfma_f32_16x16x32_fp8_fp8(a2, p2, acc_p, 0, 0, 0);
    acc_n = __builtin_amdgcn_mfma_f32_16x16x32_fp8_fp8(a2, n2, acc_n, 0, 0, 0);
    acc_p = __builtin_amdgcn_mfma_f32_16x16x32_fp8_fp8(a3, p3, acc_p, 0, 0, 0);
    acc_n = __builtin_amdgcn_mfma_f32_16x16x32_fp8_fp8(a3, n3, acc_n, 0, 0, 0);

    const bool isdiag = (h == (c >> 2));
    const int jj = c & 3;
    const float p01 = (jj & 1) ? acc_p[1] : acc_p[0];
    const float p23 = (jj & 1) ? acc_p[3] : acc_p[2];
    const float dp  = (jj & 2) ? p23 : p01;
    const float q01 = (jj & 1) ? acc_n[1] : acc_n[0];
    const float q23 = (jj & 1) ? acc_n[3] : acc_n[2];
    const float dn  = (jj & 2) ? q23 : q01;

    const float dsq_p = fmaxf(ta.x + tq.x - 2.f * dp, 0.f);
    const float dsq_n = fmaxf(ta.x + tn.x - 2.f * dn, 0.f);
    const float d_ap = sqrtf(dsq_p + EPS_F);
    const float d_an = sqrtf(dsq_n + EPS_F);
    const float b = ta.y;
    const float pl = fmaxf(d_ap - b + MARGIN_F, 0.f);
    const float nl = fmaxf(b - d_an + MARGIN_F, 0.f);

    const bool act = isdiag && bvalid;
    lt += act ? (pl + nl) : 0.f;
    lc += (act && (pl > 0.f || nl > 0.f)) ? 1.f : 0.f;
}

// ================= cooperative fused kernel =================
__global__ __launch_bounds__(256, 2) void margin_fused(
    const float* __restrict__ batch,
    const int* __restrict__ labels,
    const float* __restrict__ beta,
    const int* __restrict__ triplets,
    void* __restrict__ wsbase,
    float* __restrict__ out)
{
    float*  ws  = (float*)wsbase;
    uint2*  hb2 = (uint2*)((char*)wsbase + ACC_BYTES);
    float2* tbl = (float2*)((char*)wsbase + ACC_BYTES + HB_BYTES);
    const unsigned char* hb = (const unsigned char*)hb2;

    cg::grid_group grid = cg::this_grid();

    const int tid  = threadIdx.x;
    const int bid  = blockIdx.x;
    const int gtid = bid * 256 + tid;              // 0..131071

    // ---- Phase A: fp8 convert + norms + beta table + ws zero ----
    {
        float sq = 0.f;
        #pragma unroll
        for (int u = 0; u < 2; ++u) {
            const int i = gtid * 2 + u;            // uint2 index, 0..262143
            const float4 v0 = ((const float4*)batch)[i * 2];
            const float4 v1 = ((const float4*)batch)[i * 2 + 1];
            unsigned lo, hi;
            fp8_pack_and_sq(v0, v1, lo, hi, sq);
            hb2[i] = uint2{lo, hi};
        }
        // 8 threads per 128-float row: butterfly xor 1,2,4
        sq += __builtin_bit_cast(float, __builtin_amdgcn_ds_swizzle(__builtin_bit_cast(int, sq), 0x041F));
        sq += __builtin_bit_cast(float, __builtin_amdgcn_ds_swizzle(__builtin_bit_cast(int, sq), 0x081F));
        sq += __builtin_bit_cast(float, __builtin_amdgcn_ds_swizzle(__builtin_bit_cast(int, sq), 0x101F));
        if ((gtid & 7) == 0) {
            const int r = gtid >> 3;               // flat row = n*4+k
            tbl[(r & 3) * NN + (r >> 2)].x = sq;
        }
        if (gtid < KK * NN) {
            const int n = gtid >> 2, k = gtid & 3;
            tbl[k * NN + n].y = beta[k * NCLS + labels[n]];
        }
        if (gtid < ACC_FLOATS) ws[gtid] = 0.f;
    }

    grid.sync();

    // ---- Phase B: main ----
    {
        __shared__ float s_red[8];
        const int lane = tid & 63;
        const int wave = tid >> 6;
        const int c    = lane & 15;
        const int h    = lane >> 4;

        const int xcd      = bid & (NXCD - 1);
        const int k        = xcd >> 1;
        const int blk_in_k = (xcd & 1) * (CO_BLOCKS / NXCD) + (bid >> 3);  // 0..127
        const int wk       = blk_in_k * 4 + wave;                          // 0..511

        const float2* tbl_k = tbl + k * NN;
        float lt = 0.f, lc = 0.f;

        for (int it = 0; it < CO_ITERS; ++it) {
            const int batchi  = it * CO_WAVES_K + wk;
            const bool bvalid = (batchi < BATCHES_K);
            const int t = bvalid ? (batchi * 16 + c) : c;
            const int* tp = triplets + (k * TT + t) * 3;
            tri_mfma(hb, tbl_k, k, tp[0], tp[1], tp[2], c, h, bvalid, lt, lc);
        }

        #pragma unroll
        for (int o = 1; o <= 32; o <<= 1) {
            lt += __shfl_xor(lt, o);
            lc += __shfl_xor(lc, o);
        }
        if (lane == 0) { s_red[wave] = lt; s_red[4 + wave] = lc; }
        __syncthreads();

        if (tid == 0) {
            const float tot = s_red[0] + s_red[1] + s_red[2] + s_red[3];
            const float cnt = s_red[4] + s_red[5] + s_red[6] + s_red[7];
            const int cc = (bid >> 3) & (NCOPY - 1);
            atomicAdd(&ws[cc * 16 + k], tot);
            atomicAdd(&ws[cc * 16 + 4 + k], cnt);
        }
    }

    grid.sync();

    // ---- Phase C: final ----
    if (bid == 0 && tid < 64) {
        const int cc = tid;
        float t0 = ws[cc * 16 + 0], t1 = ws[cc * 16 + 1];
        float t2 = ws[cc * 16 + 2], t3 = ws[cc * 16 + 3];
        float c0 = ws[cc * 16 + 4], c1 = ws[cc * 16 + 5];
        float c2 = ws[cc * 16 + 6], c3 = ws[cc * 16 + 7];
        #pragma unroll
        for (int o = 1; o <= 32; o <<= 1) {
            t0 += __shfl_xor(t0, o); t1 += __shfl_xor(t1, o);
            t2 += __shfl_xor(t2, o); t3 += __shfl_xor(t3, o);
            c0 += __shfl_xor(c0, o); c1 += __shfl_xor(c1, o);
            c2 += __shfl_xor(c2, o); c3 += __shfl_xor(c3, o);
        }
        if (tid == 0) {
            const float l0 = (c0 == 0.f) ? t0 : t0 / fmaxf(c0, 1.f);
            const float l1 = (c1 == 0.f) ? t1 : t1 / fmaxf(c1, 1.f);
            const float l2 = (c2 == 0.f) ? t2 : t2 / fmaxf(c2, 1.f);
            const float l3 = (c3 == 0.f) ? t3 : t3 / fmaxf(c3, 1.f);
            out[0] = (l0 + l1 + l2 + l3) * 0.25f;
        }
    }
}

// ================= fallback path (R11, known-good) =================
__global__ __launch_bounds__(256) void prep_fb(
    const float* __restrict__ src, const int* __restrict__ labels,
    const float* __restrict__ beta,
    uint2* __restrict__ dst, float2* __restrict__ tbl, float* __restrict__ ws)
{
    const int i = blockIdx.x * blockDim.x + threadIdx.x;   // 0..262143
    const float4 v0 = ((const float4*)src)[i * 2];
    const float4 v1 = ((const float4*)src)[i * 2 + 1];
    unsigned lo, hi;
    float sq = 0.f;
    fp8_pack_and_sq(v0, v1, lo, hi, sq);
    dst[i] = uint2{lo, hi};

    sq += __builtin_bit_cast(float, __builtin_amdgcn_ds_swizzle(__builtin_bit_cast(int, sq), 0x041F));
    sq += __builtin_bit_cast(float, __builtin_amdgcn_ds_swizzle(__builtin_bit_cast(int, sq), 0x081F));
    sq += __builtin_bit_cast(float, __builtin_amdgcn_ds_swizzle(__builtin_bit_cast(int, sq), 0x101F));
    sq += __builtin_bit_cast(float, __builtin_amdgcn_ds_swizzle(__builtin_bit_cast(int, sq), 0x201F));
    if ((i & 15) == 0) {
        const int r = i >> 4;
        tbl[(r & 3) * NN + (r >> 2)].x = sq;
    }
    if (i < KK * NN) {
        const int n = i >> 2, k = i & 3;
        tbl[k * NN + n].y = beta[k * NCLS + labels[n]];
    }
    if (i < ACC_FLOATS) ws[i] = 0.f;
}

__global__ __launch_bounds__(256) void main_fb(
    const unsigned char* __restrict__ hb,
    const int* __restrict__ triplets,
    const float2* __restrict__ tbl,
    float* __restrict__ ws)
{
    __shared__ float s_red[8];
    const int tid  = threadIdx.x;
    const int lane = tid & 63;
    const int wave = tid >> 6;
    const int c    = lane & 15;
    const int h    = lane >> 4;

    const int xcd      = blockIdx.x & (NXCD - 1);
    const int k        = xcd >> 1;
    const int blk_in_k = (xcd & 1) * FB_BPK + (blockIdx.x >> 3);

    const int batchi  = blk_in_k * 4 + wave;
    const bool bvalid = (batchi < BATCHES_K);
    const int t = bvalid ? (batchi * 16 + c) : c;
    const int* tp = triplets + (k * TT + t) * 3;

    float lt = 0.f, lc = 0.f;
    tri_mfma(hb, tbl + k * NN, k, tp[0], tp[1], tp[2], c, h, bvalid, lt, lc);

    #pragma unroll
    for (int o = 1; o <= 32; o <<= 1) {
        lt += __shfl_xor(lt, o);
        lc += __shfl_xor(lc, o);
    }
    if (lane == 0) { s_red[wave] = lt; s_red[4 + wave] = lc; }
    __syncthreads();

    if (tid == 0) {
        const float tot = s_red[0] + s_red[1] + s_red[2] + s_red[3];
        const float cnt = s_red[4] + s_red[5] + s_red[6] + s_red[7];
        const int cc = (blockIdx.x >> 3) & (NCOPY - 1);
        atomicAdd(&ws[cc * 16 + k], tot);
        atomicAdd(&ws[cc * 16 + 4 + k], cnt);
    }
}

__global__ void final_fb(const float* __restrict__ ws, float* __restrict__ out) {
    if (threadIdx.x == 0 && blockIdx.x == 0) {
        float acc = 0.f;
        #pragma unroll
        for (int k = 0; k < KK; ++k) {
            float tot = 0.f, cnt = 0.f;
            for (int c = 0; c < NCOPY; ++c) {
                tot += ws[c * 16 + k];
                cnt += ws[c * 16 + 4 + k];
            }
            const float lk = (cnt == 0.f) ? tot : tot / fmaxf(cnt, 1.f);
            acc += lk;
        }
        out[0] = acc / (float)KK;
    }
}

extern "C" void kernel_launch(void* const* d_in, const int* in_sizes, int n_in,
                              void* d_out, int out_size, void* d_ws, size_t ws_size,
                              hipStream_t stream) {
    const float* batch    = (const float*)d_in[0];
    const int*   labels   = (const int*)d_in[1];
    const int*   triplets = (const int*)d_in[2];
    const float* beta     = (const float*)d_in[3];
    float* outp = (float*)d_out;
    void*  wsb  = d_ws;

    void* args[] = { (void*)&batch, (void*)&labels, (void*)&beta,
                     (void*)&triplets, (void*)&wsb, (void*)&outp };
    hipError_t err = hipLaunchCooperativeKernel((void*)margin_fused,
                                                dim3(CO_BLOCKS), dim3(256),
                                                args, 0, stream);
    if (err != hipSuccess) {
        // deterministic fallback: known-good 3-dispatch path (R11)
        float*          ws  = (float*)d_ws;
        uint2*          hb2 = (uint2*)((char*)d_ws + ACC_BYTES);
        unsigned char*  hb  = (unsigned char*)hb2;
        float2*         tbl = (float2*)((char*)d_ws + ACC_BYTES + HB_BYTES);
        prep_fb<<<1024, 256, 0, stream>>>(batch, labels, beta, hb2, tbl, ws);
        main_fb<<<FB_NBLOCKS, 256, 0, stream>>>(hb, triplets, tbl, ws);
        final_fb<<<1, 64, 0, stream>>>(ws, (float*)d_out);
    }
}

// Round 15
// 58.172 us; speedup vs baseline: 2.6198x; 2.6198x over previous
//
#include <hip/hip_runtime.h>

#define KK 4
#define TT 100000
#define NCLS 100
#define NN 4096
#define MARGIN_F 0.2f
#define EPS_F 1e-8f

#define NXCD 8
#define NBLOCKS 2048
#define WAVES_PER_K 2048              // 512 blocks/k * 4 waves
#define BATCHES_K 6250                // 6250 * 16 = 100000 triplets per k
#define ITERS 4                       // ceil(6250/2048)
#define NCOPY 64
#define ACC_FLOATS (NCOPY * 16)       // 1024 floats of accumulators
#define CTR_IDX ACC_FLOATS            // completion counter (as uint bits)
#define ACC_BYTES 8192
#define HB_BYTES (NN * KK * 128)      // fp8 batch, 2 MB (row = 128 B = 1 line)

typedef float f32x4 __attribute__((ext_vector_type(4)));

// fp32->fp8(e4m3) convert + bl[k][n]=beta[k][labels[n]] + ws/counter zero
__global__ __launch_bounds__(256) void prep(
    const float* __restrict__ src, const int* __restrict__ labels,
    const float* __restrict__ beta,
    uint2* __restrict__ dst, float* __restrict__ bl, float* __restrict__ ws)
{
    const int i = blockIdx.x * 256 + threadIdx.x;   // 0..262143, 8 floats each
    const float4 v0 = ((const float4*)src)[i * 2];
    const float4 v1 = ((const float4*)src)[i * 2 + 1];
    int lo = 0, hi = 0;
    lo = __builtin_amdgcn_cvt_pk_fp8_f32(v0.x, v0.y, lo, false);
    lo = __builtin_amdgcn_cvt_pk_fp8_f32(v0.z, v0.w, lo, true);
    hi = __builtin_amdgcn_cvt_pk_fp8_f32(v1.x, v1.y, hi, false);
    hi = __builtin_amdgcn_cvt_pk_fp8_f32(v1.z, v1.w, hi, true);
    dst[i] = uint2{(unsigned)lo, (unsigned)hi};

    if (i < KK * NN) {
        const int n = i >> 2, k = i & 3;
        bl[k * NN + n] = beta[k * NCLS + labels[n]];
    }
    if (i < ACC_FLOATS + 16) ws[i] = 0.f;   // accumulators + counter
}

__global__ __launch_bounds__(256) void margin_main(
    const unsigned char* __restrict__ hb,
    const int* __restrict__ triplets,
    const float* __restrict__ bl,
    float* __restrict__ ws,
    float* __restrict__ out)
{
    // per-wave staging: 3 operands x 16 rows x 128 B
    __shared__ __align__(16) unsigned char lds[4][3][2048];
    __shared__ float s_red[8];
    __shared__ int s_last;

    const int tid  = threadIdx.x;
    const int bid  = blockIdx.x;
    const int lane = tid & 63;
    const int wave = tid >> 6;
    const int c    = lane & 15;       // triplet column
    const int hi   = lane >> 4;       // K-subchunk (0..3)

    // XCD-pinned k
    const int xcd      = bid & (NXCD - 1);
    const int k        = xcd >> 1;
    const int blk_in_k = (xcd & 1) * 256 + (bid >> 3);   // 0..511
    const int wk       = blk_in_k * 4 + wave;            // 0..2047

    // global-load lane mapping: instr j covers rows j*8+(lane>>3), 16B cell lane&7
    const int rlo   = lane >> 3;      // 0..7
    const int cellB = lane & 7;       // 16B cell index
    // fragment-read constants: row r=c, cell C=(q*2+hC)^..., half hH
    const int r7 = c & 7;
    const int hC = hi >> 1;           // 0..1
    const int hH = (hi & 1) * 8;      // byte half within 16B cell

    unsigned char* A  = lds[wave][0];
    unsigned char* P  = lds[wave][1];
    unsigned char* Nd = lds[wave][2];

    const float* bl_k = bl + k * NN;
    const bool isdiag = (hi == (c >> 2));
    const int jj = c & 3;

    float lt = 0.f, lc = 0.f;

    for (int it = 0; it < ITERS; ++it) {
        const int batchi  = it * WAVES_PER_K + wk;
        const bool bvalid = (batchi < BATCHES_K);
        const int bb = bvalid ? batchi : 0;

        // lane holds triplet (c)'s indices
        const int* tp = triplets + (k * TT + bb * 16 + c) * 3;
        const int i0 = tp[0], i1 = tp[1], i2 = tp[2];
        const float b = bl_k[i0];                       // 1 scattered gather

        // redistribute indices to global-load lanes
        const int ra0 = __shfl(i0, rlo), ra1 = __shfl(i0, 8 + rlo);
        const int rp0 = __shfl(i1, rlo), rp1 = __shfl(i1, 8 + rlo);
        const int rn0 = __shfl(i2, rlo), rn1 = __shfl(i2, 8 + rlo);

        // 6 line-covering dwordx4 gathers (8 full rows per instruction)
        const uint4 va0 = *(const uint4*)(hb + (((ra0 << 2) + k) << 7) + cellB * 16);
        const uint4 va1 = *(const uint4*)(hb + (((ra1 << 2) + k) << 7) + cellB * 16);
        const uint4 vp0 = *(const uint4*)(hb + (((rp0 << 2) + k) << 7) + cellB * 16);
        const uint4 vp1 = *(const uint4*)(hb + (((rp1 << 2) + k) << 7) + cellB * 16);
        const uint4 vn0 = *(const uint4*)(hb + (((rn0 << 2) + k) << 7) + cellB * 16);
        const uint4 vn1 = *(const uint4*)(hb + (((rn1 << 2) + k) << 7) + cellB * 16);

        // stage to LDS, 16B-cell XOR swizzle: cell stored at (B ^ (row&7))
        const int w0 = rlo, w1 = 8 + rlo;
        const int o0 = w0 * 128 + ((cellB ^ (w0 & 7)) << 4);
        const int o1 = w1 * 128 + ((cellB ^ (w1 & 7)) << 4);
        *(uint4*)(A + o0)  = va0;  *(uint4*)(A + o1)  = va1;
        *(uint4*)(P + o0)  = vp0;  *(uint4*)(P + o1)  = vp1;
        *(uint4*)(Nd + o0) = vn0;  *(uint4*)(Nd + o1) = vn1;

        // fragments + 5 MFMA products (ap, an, aa, pp, nn)
        f32x4 ap = {0,0,0,0}, an = {0,0,0,0};
        f32x4 aa = {0,0,0,0}, pp = {0,0,0,0}, nn = {0,0,0,0};
        #pragma unroll
        for (int q = 0; q < 4; ++q) {
            const int off = c * 128 + ((((q << 1) + hC) ^ r7) << 4) + hH;
            const long fa = *(const long*)(A + off);
            const long fp = *(const long*)(P + off);
            const long fn = *(const long*)(Nd + off);
            ap = __builtin_amdgcn_mfma_f32_16x16x32_fp8_fp8(fa, fp, ap, 0, 0, 0);
            an = __builtin_amdgcn_mfma_f32_16x16x32_fp8_fp8(fa, fn, an, 0, 0, 0);
            aa = __builtin_amdgcn_mfma_f32_16x16x32_fp8_fp8(fa, fa, aa, 0, 0, 0);
            pp = __builtin_amdgcn_mfma_f32_16x16x32_fp8_fp8(fp, fp, pp, 0, 0, 0);
            nn = __builtin_amdgcn_mfma_f32_16x16x32_fp8_fp8(fn, fn, nn, 0, 0, 0);
        }

        // diagonal element jj on diag lanes; static selects (no dyn index)
        #define SEL(v) ((jj & 2) ? ((jj & 1) ? v[3] : v[2]) : ((jj & 1) ? v[1] : v[0]))
        const float dap2 = SEL(aa) + SEL(pp) - 2.f * SEL(ap);
        const float dan2 = SEL(aa) + SEL(nn) - 2.f * SEL(an);
        #undef SEL
        const float d_ap = sqrtf(fmaxf(dap2, 0.f) + EPS_F);
        const float d_an = sqrtf(fmaxf(dan2, 0.f) + EPS_F);
        const float pl = fmaxf(d_ap - b + MARGIN_F, 0.f);
        const float nl = fmaxf(b - d_an + MARGIN_F, 0.f);

        const bool act = isdiag && bvalid;
        lt += act ? (pl + nl) : 0.f;
        lc += (act && (pl > 0.f || nl > 0.f)) ? 1.f : 0.f;
    }

    // wave reduce (16 diag lanes hold values)
    #pragma unroll
    for (int o = 1; o <= 32; o <<= 1) {
        lt += __shfl_xor(lt, o);
        lc += __shfl_xor(lc, o);
    }
    if (lane == 0) { s_red[wave] = lt; s_red[4 + wave] = lc; }
    __syncthreads();

    if (tid == 0) {
        const float tot = s_red[0] + s_red[1] + s_red[2] + s_red[3];
        const float cnt = s_red[4] + s_red[5] + s_red[6] + s_red[7];
        const int cc = (bid >> 3) & (NCOPY - 1);
        atomicAdd(&ws[cc * 16 + k], tot);
        atomicAdd(&ws[cc * 16 + 4 + k], cnt);
        __threadfence();
        const unsigned done = atomicAdd((unsigned*)&ws[CTR_IDX], 1u);
        s_last = (done == (unsigned)(NBLOCKS - 1)) ? 1 : 0;
    }
    __syncthreads();

    // last block performs the final reduction (atomic-reads for coherence)
    if (s_last && tid < 64) {
        float t0 = atomicAdd(&ws[tid * 16 + 0], 0.f);
        float t1 = atomicAdd(&ws[tid * 16 + 1], 0.f);
        float t2 = atomicAdd(&ws[tid * 16 + 2], 0.f);
        float t3 = atomicAdd(&ws[tid * 16 + 3], 0.f);
        float c0 = atomicAdd(&ws[tid * 16 + 4], 0.f);
        float c1 = atomicAdd(&ws[tid * 16 + 5], 0.f);
        float c2 = atomicAdd(&ws[tid * 16 + 6], 0.f);
        float c3 = atomicAdd(&ws[tid * 16 + 7], 0.f);
        #pragma unroll
        for (int o = 1; o <= 32; o <<= 1) {
            t0 += __shfl_xor(t0, o); t1 += __shfl_xor(t1, o);
            t2 += __shfl_xor(t2, o); t3 += __shfl_xor(t3, o);
            c0 += __shfl_xor(c0, o); c1 += __shfl_xor(c1, o);
            c2 += __shfl_xor(c2, o); c3 += __shfl_xor(c3, o);
        }
        if (tid == 0) {
            const float l0 = (c0 == 0.f) ? t0 : t0 / fmaxf(c0, 1.f);
            const float l1 = (c1 == 0.f) ? t1 : t1 / fmaxf(c1, 1.f);
            const float l2 = (c2 == 0.f) ? t2 : t2 / fmaxf(c2, 1.f);
            const float l3 = (c3 == 0.f) ? t3 : t3 / fmaxf(c3, 1.f);
            out[0] = (l0 + l1 + l2 + l3) * 0.25f;
        }
    }
}

extern "C" void kernel_launch(void* const* d_in, const int* in_sizes, int n_in,
                              void* d_out, int out_size, void* d_ws, size_t ws_size,
                              hipStream_t stream) {
    const float* batch    = (const float*)d_in[0];
    const int*   labels   = (const int*)d_in[1];
    const int*   triplets = (const int*)d_in[2];
    const float* beta     = (const float*)d_in[3];

    float*          ws  = (float*)d_ws;
    uint2*          hb2 = (uint2*)((char*)d_ws + ACC_BYTES);
    unsigned char*  hb  = (unsigned char*)hb2;
    float*          bl  = (float*)((char*)d_ws + ACC_BYTES + HB_BYTES);

    prep<<<1024, 256, 0, stream>>>(batch, labels, beta, hb2, bl, ws);
    margin_main<<<NBLOCKS, 256, 0, stream>>>(hb, triplets, bl, ws, (float*)d_out);
}